// Round 1
// baseline (1787.341 us; speedup 1.0000x reference)
//
#include <hip/hip_runtime.h>
#include <hip/hip_bf16.h>

#define IN_DIM 128
#define HID 8

// ---------------- degree histogram (edge-parallel) ----------------
__global__ void deg_kernel(const int* __restrict__ src, const int* __restrict__ dst,
                           float* __restrict__ deg_out, float* __restrict__ deg_in, int E) {
    int e = blockIdx.x * blockDim.x + threadIdx.x;
    if (e < E) {
        unsafeAtomicAdd(&deg_out[src[e]], 1.0f);
        unsafeAtomicAdd(&deg_in[dst[e]], 1.0f);
    }
}

// ---------------- conv1: h = (x * norm_out) @ W1  [N,128]->[N,8] ----------------
// 8 threads per node; lane owns k in {lane*4 + 32*m, m=0..3} (float4 chunks).
// W1 staged transposed+padded in LDS: wt[j*132 + k] -> conflict-free b128 reads.
__global__ __launch_bounds__(256) void conv1_kernel(
        const float* __restrict__ x, const float* __restrict__ W1,
        const float* __restrict__ deg_out, float* __restrict__ h, int N) {
    __shared__ float wt[HID * 132];
    int t = threadIdx.x;
    for (int i = t; i < IN_DIM * HID; i += 256) {
        int k = i >> 3, j = i & 7;
        wt[j * 132 + k] = W1[i];
    }
    __syncthreads();
    int grp = t >> 3, lane = t & 7;
    int node = blockIdx.x * 32 + grp;
    if (node >= N) return;
    const float4* xp = reinterpret_cast<const float4*>(x + (size_t)node * IN_DIM);
    float4 xv[4];
    #pragma unroll
    for (int m = 0; m < 4; ++m) xv[m] = xp[lane + m * 8];
    float acc[HID];
    #pragma unroll
    for (int j = 0; j < HID; ++j) acc[j] = 0.f;
    #pragma unroll
    for (int j = 0; j < HID; ++j) {
        #pragma unroll
        for (int m = 0; m < 4; ++m) {
            float4 wv = *reinterpret_cast<const float4*>(&wt[j * 132 + lane * 4 + m * 32]);
            acc[j] += xv[m].x * wv.x + xv[m].y * wv.y + xv[m].z * wv.z + xv[m].w * wv.w;
        }
    }
    // reduce across the 8 lanes of this node's group (consecutive lane ids)
    #pragma unroll
    for (int off = 1; off < 8; off <<= 1) {
        #pragma unroll
        for (int j = 0; j < HID; ++j) acc[j] += __shfl_xor(acc[j], off, 64);
    }
    if (lane == 0) {
        float nrm = rsqrtf(fmaxf(deg_out[node], 1.0f));
        float4* hp = reinterpret_cast<float4*>(h + (size_t)node * HID);
        hp[0] = make_float4(acc[0] * nrm, acc[1] * nrm, acc[2] * nrm, acc[3] * nrm);
        hp[1] = make_float4(acc[4] * nrm, acc[5] * nrm, acc[6] * nrm, acc[7] * nrm);
    }
}

// ---------------- conv1 aggregation: agg1[dst] += h[src] (8 floats) ----------------
__global__ void scatter1_kernel(const int* __restrict__ src, const int* __restrict__ dst,
                                const float* __restrict__ h, float* __restrict__ agg1, int E) {
    int e = blockIdx.x * blockDim.x + threadIdx.x;
    if (e >= E) return;
    int s = src[e], d = dst[e];
    const float4* hp = reinterpret_cast<const float4*>(h + (size_t)s * HID);
    float4 a = hp[0], b = hp[1];
    float* ap = agg1 + (size_t)d * HID;
    unsafeAtomicAdd(ap + 0, a.x);
    unsafeAtomicAdd(ap + 1, a.y);
    unsafeAtomicAdd(ap + 2, a.z);
    unsafeAtomicAdd(ap + 3, a.w);
    unsafeAtomicAdd(ap + 4, b.x);
    unsafeAtomicAdd(ap + 5, b.y);
    unsafeAtomicAdd(ap + 6, b.z);
    unsafeAtomicAdd(ap + 7, b.w);
}

// ---------------- finish conv1 (norm_in, +b1, relu) then conv2 weight+norm_out ----------------
__global__ void mid_kernel(const float* __restrict__ agg1, const float* __restrict__ deg_out,
                           const float* __restrict__ deg_in, const float* __restrict__ b1,
                           const float* __restrict__ W2, float* __restrict__ h2, int N) {
    int i = blockIdx.x * blockDim.x + threadIdx.x;
    if (i >= N) return;
    float nin = rsqrtf(fmaxf(deg_in[i], 1.0f));
    float nout = rsqrtf(fmaxf(deg_out[i], 1.0f));
    const float4* ap = reinterpret_cast<const float4*>(agg1 + (size_t)i * HID);
    float4 a = ap[0], b = ap[1];
    float dotv = 0.f, y;
    y = fmaxf(a.x * nin + b1[0], 0.f); dotv += y * W2[0];
    y = fmaxf(a.y * nin + b1[1], 0.f); dotv += y * W2[1];
    y = fmaxf(a.z * nin + b1[2], 0.f); dotv += y * W2[2];
    y = fmaxf(a.w * nin + b1[3], 0.f); dotv += y * W2[3];
    y = fmaxf(b.x * nin + b1[4], 0.f); dotv += y * W2[4];
    y = fmaxf(b.y * nin + b1[5], 0.f); dotv += y * W2[5];
    y = fmaxf(b.z * nin + b1[6], 0.f); dotv += y * W2[6];
    y = fmaxf(b.w * nin + b1[7], 0.f); dotv += y * W2[7];
    h2[i] = dotv * nout;
}

// ---------------- conv2 aggregation: agg2[dst] += h2[src] (1 float) ----------------
__global__ void scatter2_kernel(const int* __restrict__ src, const int* __restrict__ dst,
                                const float* __restrict__ h2, float* __restrict__ agg2, int E) {
    int e = blockIdx.x * blockDim.x + threadIdx.x;
    if (e >= E) return;
    unsafeAtomicAdd(&agg2[dst[e]], h2[src[e]]);
}

// ---------------- final: out = agg2 * norm_in + b2 ----------------
__global__ void final_kernel(const float* __restrict__ agg2, const float* __restrict__ deg_in,
                             const float* __restrict__ b2, float* __restrict__ out, int N) {
    int i = blockIdx.x * blockDim.x + threadIdx.x;
    if (i >= N) return;
    out[i] = agg2[i] * rsqrtf(fmaxf(deg_in[i], 1.0f)) + b2[0];
}

extern "C" void kernel_launch(void* const* d_in, const int* in_sizes, int n_in,
                              void* d_out, int out_size, void* d_ws, size_t ws_size,
                              hipStream_t stream) {
    const float* x  = (const float*)d_in[0];
    const int* src  = (const int*)d_in[1];
    const int* dst  = (const int*)d_in[2];
    const float* W1 = (const float*)d_in[3];
    const float* b1 = (const float*)d_in[4];
    const float* W2 = (const float*)d_in[5];
    const float* b2 = (const float*)d_in[6];
    float* out = (float*)d_out;

    const int N = out_size;      // 100000
    const int E = in_sizes[1];   // 3200000

    // workspace layout (floats):
    // [deg_out N][deg_in N][agg1 8N][agg2 N]  <- zeroed (11N floats)
    // [h 8N][h2 N]                            <- fully overwritten
    float* ws      = (float*)d_ws;
    float* deg_out = ws;
    float* deg_in  = ws + (size_t)N;
    float* agg1    = ws + 2 * (size_t)N;
    float* agg2    = ws + 10 * (size_t)N;
    float* h       = ws + 11 * (size_t)N;
    float* h2      = ws + 19 * (size_t)N;

    hipMemsetAsync(ws, 0, 11 * (size_t)N * sizeof(float), stream);

    int eb = (E + 255) / 256;
    int nb = (N + 255) / 256;
    deg_kernel<<<eb, 256, 0, stream>>>(src, dst, deg_out, deg_in, E);
    conv1_kernel<<<(N + 31) / 32, 256, 0, stream>>>(x, W1, deg_out, h, N);
    scatter1_kernel<<<eb, 256, 0, stream>>>(src, dst, h, agg1, E);
    mid_kernel<<<nb, 256, 0, stream>>>(agg1, deg_out, deg_in, b1, W2, h2, N);
    scatter2_kernel<<<eb, 256, 0, stream>>>(src, dst, h2, agg2, E);
    final_kernel<<<nb, 256, 0, stream>>>(agg2, deg_in, b2, out, N);
}

// Round 2
// 326.608 us; speedup vs baseline: 5.4724x; 5.4724x over previous
//
#include <hip/hip_runtime.h>
#include <hip/hip_bf16.h>

#define IN_DIM 128
#define HID 8
#define RW 128          // node range width (one LDS tile per range)
#define MAXR 1024       // max ranges (N<=131072)
#define CCH 512         // edge chunks for count/scatter

// ---------------- pass1: per-chunk range histograms (no global atomics) ----------------
__global__ __launch_bounds__(256) void pass1_count(const int* __restrict__ src, const int* __restrict__ dst,
        int* __restrict__ cnt_d, int* __restrict__ cnt_s, int E, int R, int chunk) {
    __shared__ int cd[MAXR], cs[MAXR];
    int t = threadIdx.x, c = blockIdx.x;
    for (int i = t; i < R; i += 256) { cd[i] = 0; cs[i] = 0; }
    __syncthreads();
    int lo = c * chunk, hi = min(lo + chunk, E);
    for (int i = lo + t; i < hi; i += 256) {
        atomicAdd(&cd[dst[i] >> 7], 1);
        atomicAdd(&cs[src[i] >> 7], 1);
    }
    __syncthreads();
    for (int i = t; i < R; i += 256) {
        cnt_d[(size_t)c * R + i] = cd[i];
        cnt_s[(size_t)c * R + i] = cs[i];
    }
}

// ---------------- scan1: per-range exclusive scan over chunks (in place) + totals ----------------
__global__ __launch_bounds__(256) void scan1_kernel(int* __restrict__ cnt_d, int* __restrict__ cnt_s,
        int* __restrict__ tot_d, int* __restrict__ tot_s, int R) {
    int r = blockIdx.x;
    int* cnt = blockIdx.y ? cnt_s : cnt_d;
    int* tot = blockIdx.y ? tot_s : tot_d;
    __shared__ int sh[256];
    int t = threadIdx.x;
    // CCH=512: each thread owns 2 consecutive chunks
    int e0 = cnt[(size_t)(2 * t) * R + r];
    int e1 = cnt[(size_t)(2 * t + 1) * R + r];
    int s = e0 + e1;
    sh[t] = s;
    __syncthreads();
    for (int off = 1; off < 256; off <<= 1) {
        int v = (t >= off) ? sh[t - off] : 0;
        __syncthreads();
        sh[t] += v;
        __syncthreads();
    }
    int exc = sh[t] - s;
    cnt[(size_t)(2 * t) * R + r] = exc;
    cnt[(size_t)(2 * t + 1) * R + r] = exc + e0;
    if (t == 255) tot[r] = sh[255];
}

// ---------------- scan2: exclusive scan of range totals -> bucket bases ----------------
__global__ __launch_bounds__(256) void scan2_kernel(const int* __restrict__ tot_d, const int* __restrict__ tot_s,
        int* __restrict__ base_d, int* __restrict__ base_s, int R) {
    const int* tot = blockIdx.x ? tot_s : tot_d;
    int* base = blockIdx.x ? base_s : base_d;
    __shared__ int sh[256];
    int t = threadIdx.x;
    int K = (R + 255) / 256;  // <=4 for MAXR
    int vals[4];
    int s = 0;
    for (int k = 0; k < K; ++k) {
        int i = t * K + k;
        int v = (i < R) ? tot[i] : 0;
        vals[k] = v; s += v;
    }
    sh[t] = s;
    __syncthreads();
    for (int off = 1; off < 256; off <<= 1) {
        int v = (t >= off) ? sh[t - off] : 0;
        __syncthreads();
        sh[t] += v;
        __syncthreads();
    }
    int exc = sh[t] - s;
    for (int k = 0; k < K; ++k) {
        int i = t * K + k;
        if (i < R) base[i] = exc;
        exc += vals[k];
    }
    if (t == 255) base[R] = sh[255];
}

// ---------------- scatter: bucket edges by dst range (packed) + src locals (bytes) ----------------
__global__ __launch_bounds__(256) void scatter_kernel(const int* __restrict__ src, const int* __restrict__ dst,
        const int* __restrict__ cnt_d, const int* __restrict__ cnt_s,
        const int* __restrict__ base_d, const int* __restrict__ base_s,
        unsigned int* __restrict__ bucket_d, unsigned char* __restrict__ bucket_s,
        int E, int R, int chunk) {
    __shared__ int od[MAXR], os[MAXR];
    int t = threadIdx.x, c = blockIdx.x;
    for (int i = t; i < R; i += 256) {
        od[i] = base_d[i] + cnt_d[(size_t)c * R + i];
        os[i] = base_s[i] + cnt_s[(size_t)c * R + i];
    }
    __syncthreads();
    int lo = c * chunk, hi = min(lo + chunk, E);
    for (int i = lo + t; i < hi; i += 256) {
        int s = src[i], d = dst[i];
        int pd = atomicAdd(&od[d >> 7], 1);
        bucket_d[pd] = ((unsigned)s << 7) | (unsigned)(d & 127);
        int ps = atomicAdd(&os[s >> 7], 1);
        bucket_s[ps] = (unsigned char)(s & 127);
    }
}

// ---------------- deg_out: per-range count of src locals ----------------
__global__ __launch_bounds__(256) void degout_kernel(const unsigned char* __restrict__ bucket_s,
        const int* __restrict__ base_s, float* __restrict__ deg_out, int N) {
    __shared__ int cnt[RW];
    int r = blockIdx.x, t = threadIdx.x;
    if (t < RW) cnt[t] = 0;
    __syncthreads();
    int lo = base_s[r], hi = base_s[r + 1];
    for (int i = lo + t; i < hi; i += 256) atomicAdd(&cnt[bucket_s[i]], 1);
    __syncthreads();
    if (t < RW) {
        int node = r * RW + t;
        if (node < N) deg_out[node] = (float)cnt[t];
    }
}

// ---------------- conv1: h = (x * norm_out) @ W1  [N,128]->[N,8] ----------------
__global__ __launch_bounds__(256) void conv1_kernel(
        const float* __restrict__ x, const float* __restrict__ W1,
        const float* __restrict__ deg_out, float* __restrict__ h, int N) {
    __shared__ float wt[HID * 132];
    int t = threadIdx.x;
    for (int i = t; i < IN_DIM * HID; i += 256) {
        int k = i >> 3, j = i & 7;
        wt[j * 132 + k] = W1[i];
    }
    __syncthreads();
    int grp = t >> 3, lane = t & 7;
    int node = blockIdx.x * 32 + grp;
    if (node >= N) return;
    const float4* xp = reinterpret_cast<const float4*>(x + (size_t)node * IN_DIM);
    float4 xv[4];
    #pragma unroll
    for (int m = 0; m < 4; ++m) xv[m] = xp[lane + m * 8];
    float acc[HID];
    #pragma unroll
    for (int j = 0; j < HID; ++j) acc[j] = 0.f;
    #pragma unroll
    for (int j = 0; j < HID; ++j) {
        #pragma unroll
        for (int m = 0; m < 4; ++m) {
            float4 wv = *reinterpret_cast<const float4*>(&wt[j * 132 + lane * 4 + m * 32]);
            acc[j] += xv[m].x * wv.x + xv[m].y * wv.y + xv[m].z * wv.z + xv[m].w * wv.w;
        }
    }
    #pragma unroll
    for (int off = 1; off < 8; off <<= 1) {
        #pragma unroll
        for (int j = 0; j < HID; ++j) acc[j] += __shfl_xor(acc[j], off, 64);
    }
    if (lane == 0) {
        float nrm = rsqrtf(fmaxf(deg_out[node], 1.0f));
        float4* hp = reinterpret_cast<float4*>(h + (size_t)node * HID);
        hp[0] = make_float4(acc[0] * nrm, acc[1] * nrm, acc[2] * nrm, acc[3] * nrm);
        hp[1] = make_float4(acc[4] * nrm, acc[5] * nrm, acc[6] * nrm, acc[7] * nrm);
    }
}

// ---------------- agg1 (+deg_in, norm_in, bias, relu, W2 dot, norm_out) -> h2 ----------------
__global__ __launch_bounds__(256) void agg1_kernel(const unsigned int* __restrict__ bucket_d,
        const int* __restrict__ base_d, const float* __restrict__ h,
        const float* __restrict__ deg_out, const float* __restrict__ b1, const float* __restrict__ W2,
        float* __restrict__ h2, float* __restrict__ deg_in, int N) {
    __shared__ float tile[HID][RW];
    __shared__ int cnt[RW];
    int r = blockIdx.x, t = threadIdx.x;
    for (int i = t; i < HID * RW; i += 256) tile[i >> 7][i & 127] = 0.f;
    if (t < RW) cnt[t] = 0;
    __syncthreads();
    int lo = base_d[r], hi = base_d[r + 1];
    for (int i = lo + t; i < hi; i += 256) {
        unsigned p = bucket_d[i];
        int s = p >> 7, l = p & 127;
        const float4* hp = reinterpret_cast<const float4*>(h + (size_t)s * HID);
        float4 a = hp[0], b = hp[1];
        atomicAdd(&cnt[l], 1);
        atomicAdd(&tile[0][l], a.x);
        atomicAdd(&tile[1][l], a.y);
        atomicAdd(&tile[2][l], a.z);
        atomicAdd(&tile[3][l], a.w);
        atomicAdd(&tile[4][l], b.x);
        atomicAdd(&tile[5][l], b.y);
        atomicAdd(&tile[6][l], b.z);
        atomicAdd(&tile[7][l], b.w);
    }
    __syncthreads();
    if (t < RW) {
        int node = r * RW + t;
        if (node < N) {
            float din = (float)cnt[t];
            deg_in[node] = din;
            float nin = rsqrtf(fmaxf(din, 1.f));
            float nout = rsqrtf(fmaxf(deg_out[node], 1.f));
            float dot = 0.f;
            #pragma unroll
            for (int j = 0; j < HID; ++j) {
                float y = fmaxf(tile[j][t] * nin + b1[j], 0.f);
                dot += y * W2[j];
            }
            h2[node] = dot * nout;
        }
    }
}

// ---------------- agg2 (+final norm_in and bias) -> out ----------------
__global__ __launch_bounds__(256) void agg2_kernel(const unsigned int* __restrict__ bucket_d,
        const int* __restrict__ base_d, const float* __restrict__ h2,
        const float* __restrict__ deg_in, const float* __restrict__ b2,
        float* __restrict__ out, int N) {
    __shared__ float tile[RW];
    int r = blockIdx.x, t = threadIdx.x;
    if (t < RW) tile[t] = 0.f;
    __syncthreads();
    int lo = base_d[r], hi = base_d[r + 1];
    for (int i = lo + t; i < hi; i += 256) {
        unsigned p = bucket_d[i];
        atomicAdd(&tile[p & 127], h2[p >> 7]);
    }
    __syncthreads();
    if (t < RW) {
        int node = r * RW + t;
        if (node < N) out[node] = tile[t] * rsqrtf(fmaxf(deg_in[node], 1.f)) + b2[0];
    }
}

extern "C" void kernel_launch(void* const* d_in, const int* in_sizes, int n_in,
                              void* d_out, int out_size, void* d_ws, size_t ws_size,
                              hipStream_t stream) {
    const float* x  = (const float*)d_in[0];
    const int* src  = (const int*)d_in[1];
    const int* dst  = (const int*)d_in[2];
    const float* W1 = (const float*)d_in[3];
    const float* b1 = (const float*)d_in[4];
    const float* W2 = (const float*)d_in[5];
    const float* b2 = (const float*)d_in[6];
    float* out = (float*)d_out;

    const int N = out_size;      // 100000
    const int E = in_sizes[1];   // 3200000
    const int R = (N + RW - 1) / RW;          // 782
    const int chunk = (E + CCH - 1) / CCH;    // 6250

    // workspace layout
    float* ws      = (float*)d_ws;
    float* deg_out = ws;                       // N
    float* deg_in  = deg_out + N;              // N
    float* h       = deg_in + N;               // 8N
    float* h2      = h + 8 * (size_t)N;        // N
    int*   cnt_d   = (int*)(h2 + N);           // CCH*R
    int*   cnt_s   = cnt_d + (size_t)CCH * R;  // CCH*R
    int*   tot_d   = cnt_s + (size_t)CCH * R;  // R
    int*   tot_s   = tot_d + R;                // R
    int*   base_d  = tot_s + R;                // R+1
    int*   base_s  = base_d + R + 1;           // R+1
    unsigned int*  bucket_d = (unsigned int*)(base_s + R + 1);   // E
    unsigned char* bucket_s = (unsigned char*)(bucket_d + E);    // E bytes

    pass1_count<<<CCH, 256, 0, stream>>>(src, dst, cnt_d, cnt_s, E, R, chunk);
    scan1_kernel<<<dim3(R, 2), 256, 0, stream>>>(cnt_d, cnt_s, tot_d, tot_s, R);
    scan2_kernel<<<2, 256, 0, stream>>>(tot_d, tot_s, base_d, base_s, R);
    scatter_kernel<<<CCH, 256, 0, stream>>>(src, dst, cnt_d, cnt_s, base_d, base_s,
                                            bucket_d, bucket_s, E, R, chunk);
    degout_kernel<<<R, 256, 0, stream>>>(bucket_s, base_s, deg_out, N);
    conv1_kernel<<<(N + 31) / 32, 256, 0, stream>>>(x, W1, deg_out, h, N);
    agg1_kernel<<<R, 256, 0, stream>>>(bucket_d, base_d, h, deg_out, b1, W2, h2, deg_in, N);
    agg2_kernel<<<R, 256, 0, stream>>>(bucket_d, base_d, h2, deg_in, b2, out, N);
}

// Round 3
// 302.475 us; speedup vs baseline: 5.9090x; 1.0798x over previous
//
#include <hip/hip_runtime.h>
#include <hip/hip_bf16.h>
#include <hip/hip_fp16.h>

#define IN_DIM 128
#define HID 8
#define RW 128          // node range width (one LDS tile per range)
#define MAXR 1024       // max ranges (N<=131072)
#define CCH 512         // edge chunks for count/scatter
#define SEG 4           // segments per bucket for agg parallelism

// ---------------- pass1: per-chunk range histograms (no global atomics) ----------------
__global__ __launch_bounds__(256) void pass1_count(const int* __restrict__ src, const int* __restrict__ dst,
        int* __restrict__ cnt_d, int* __restrict__ cnt_s, int E, int R, int chunk) {
    __shared__ int cd[MAXR], cs[MAXR];
    int t = threadIdx.x, c = blockIdx.x;
    for (int i = t; i < R; i += 256) { cd[i] = 0; cs[i] = 0; }
    __syncthreads();
    int lo = c * chunk, hi = min(lo + chunk, E);
    for (int i = lo + t; i < hi; i += 256) {
        atomicAdd(&cd[dst[i] >> 7], 1);
        atomicAdd(&cs[src[i] >> 7], 1);
    }
    __syncthreads();
    for (int i = t; i < R; i += 256) {
        cnt_d[(size_t)c * R + i] = cd[i];
        cnt_s[(size_t)c * R + i] = cs[i];
    }
}

// ---------------- scan1: per-range exclusive scan over chunks (in place) + totals ----------------
__global__ __launch_bounds__(256) void scan1_kernel(int* __restrict__ cnt_d, int* __restrict__ cnt_s,
        int* __restrict__ tot_d, int* __restrict__ tot_s, int R) {
    int r = blockIdx.x;
    int* cnt = blockIdx.y ? cnt_s : cnt_d;
    int* tot = blockIdx.y ? tot_s : tot_d;
    __shared__ int sh[256];
    int t = threadIdx.x;
    int e0 = cnt[(size_t)(2 * t) * R + r];
    int e1 = cnt[(size_t)(2 * t + 1) * R + r];
    int s = e0 + e1;
    sh[t] = s;
    __syncthreads();
    for (int off = 1; off < 256; off <<= 1) {
        int v = (t >= off) ? sh[t - off] : 0;
        __syncthreads();
        sh[t] += v;
        __syncthreads();
    }
    int exc = sh[t] - s;
    cnt[(size_t)(2 * t) * R + r] = exc;
    cnt[(size_t)(2 * t + 1) * R + r] = exc + e0;
    if (t == 255) tot[r] = sh[255];
}

// ---------------- scan2: exclusive scan of range totals -> bucket bases ----------------
__global__ __launch_bounds__(256) void scan2_kernel(const int* __restrict__ tot_d, const int* __restrict__ tot_s,
        int* __restrict__ base_d, int* __restrict__ base_s, int R) {
    const int* tot = blockIdx.x ? tot_s : tot_d;
    int* base = blockIdx.x ? base_s : base_d;
    __shared__ int sh[256];
    int t = threadIdx.x;
    int K = (R + 255) / 256;
    int vals[4];
    int s = 0;
    for (int k = 0; k < K; ++k) {
        int i = t * K + k;
        int v = (i < R) ? tot[i] : 0;
        vals[k] = v; s += v;
    }
    sh[t] = s;
    __syncthreads();
    for (int off = 1; off < 256; off <<= 1) {
        int v = (t >= off) ? sh[t - off] : 0;
        __syncthreads();
        sh[t] += v;
        __syncthreads();
    }
    int exc = sh[t] - s;
    for (int k = 0; k < K; ++k) {
        int i = t * K + k;
        if (i < R) base[i] = exc;
        exc += vals[k];
    }
    if (t == 255) base[R] = sh[255];
}

// ---------------- scatter: bucket edges by dst range (packed) + src locals (bytes) ----------------
__global__ __launch_bounds__(256) void scatter_kernel(const int* __restrict__ src, const int* __restrict__ dst,
        const int* __restrict__ cnt_d, const int* __restrict__ cnt_s,
        const int* __restrict__ base_d, const int* __restrict__ base_s,
        unsigned int* __restrict__ bucket_d, unsigned char* __restrict__ bucket_s,
        int E, int R, int chunk) {
    __shared__ int od[MAXR], os[MAXR];
    int t = threadIdx.x, c = blockIdx.x;
    for (int i = t; i < R; i += 256) {
        od[i] = base_d[i] + cnt_d[(size_t)c * R + i];
        os[i] = base_s[i] + cnt_s[(size_t)c * R + i];
    }
    __syncthreads();
    int lo = c * chunk, hi = min(lo + chunk, E);
    for (int i = lo + t; i < hi; i += 256) {
        int s = src[i], d = dst[i];
        int pd = atomicAdd(&od[d >> 7], 1);
        bucket_d[pd] = ((unsigned)s << 7) | (unsigned)(d & 127);
        int ps = atomicAdd(&os[s >> 7], 1);
        bucket_s[ps] = (unsigned char)(s & 127);
    }
}

// ---------------- deg_out: per-range count of src locals ----------------
__global__ __launch_bounds__(256) void degout_kernel(const unsigned char* __restrict__ bucket_s,
        const int* __restrict__ base_s, float* __restrict__ deg_out, int N) {
    __shared__ int cnt[RW];
    int r = blockIdx.x, t = threadIdx.x;
    if (t < RW) cnt[t] = 0;
    __syncthreads();
    int lo = base_s[r], hi = base_s[r + 1];
    for (int i = lo + t; i < hi; i += 256) atomicAdd(&cnt[bucket_s[i]], 1);
    __syncthreads();
    if (t < RW) {
        int node = r * RW + t;
        if (node < N) deg_out[node] = (float)cnt[t];
    }
}

// ---------------- conv1: h = (x * norm_out) @ W1, packed to f16x8 (16B/node) ----------------
__global__ __launch_bounds__(256) void conv1_kernel(
        const float* __restrict__ x, const float* __restrict__ W1,
        const float* __restrict__ deg_out, uint4* __restrict__ h4, int N) {
    __shared__ float wt[HID * 132];
    int t = threadIdx.x;
    for (int i = t; i < IN_DIM * HID; i += 256) {
        int k = i >> 3, j = i & 7;
        wt[j * 132 + k] = W1[i];
    }
    __syncthreads();
    int grp = t >> 3, lane = t & 7;
    int node = blockIdx.x * 32 + grp;
    if (node >= N) return;
    const float4* xp = reinterpret_cast<const float4*>(x + (size_t)node * IN_DIM);
    float4 xv[4];
    #pragma unroll
    for (int m = 0; m < 4; ++m) xv[m] = xp[lane + m * 8];
    float acc[HID];
    #pragma unroll
    for (int j = 0; j < HID; ++j) acc[j] = 0.f;
    #pragma unroll
    for (int j = 0; j < HID; ++j) {
        #pragma unroll
        for (int m = 0; m < 4; ++m) {
            float4 wv = *reinterpret_cast<const float4*>(&wt[j * 132 + lane * 4 + m * 32]);
            acc[j] += xv[m].x * wv.x + xv[m].y * wv.y + xv[m].z * wv.z + xv[m].w * wv.w;
        }
    }
    #pragma unroll
    for (int off = 1; off < 8; off <<= 1) {
        #pragma unroll
        for (int j = 0; j < HID; ++j) acc[j] += __shfl_xor(acc[j], off, 64);
    }
    if (lane == 0) {
        float nrm = rsqrtf(fmaxf(deg_out[node], 1.0f));
        __half2 p0 = __floats2half2_rn(acc[0] * nrm, acc[1] * nrm);
        __half2 p1 = __floats2half2_rn(acc[2] * nrm, acc[3] * nrm);
        __half2 p2 = __floats2half2_rn(acc[4] * nrm, acc[5] * nrm);
        __half2 p3 = __floats2half2_rn(acc[6] * nrm, acc[7] * nrm);
        uint4 o;
        o.x = *reinterpret_cast<unsigned*>(&p0);
        o.y = *reinterpret_cast<unsigned*>(&p1);
        o.z = *reinterpret_cast<unsigned*>(&p2);
        o.w = *reinterpret_cast<unsigned*>(&p3);
        h4[node] = o;
    }
}

// ---------------- agg1: segmented edge aggregation into LDS, dump partials ----------------
__device__ __forceinline__ void addEdge1(float* tile, int* cnt, unsigned p, uint4 g) {
    int l = p & 127;
    __half2 q0 = *reinterpret_cast<__half2*>(&g.x);
    __half2 q1 = *reinterpret_cast<__half2*>(&g.y);
    __half2 q2 = *reinterpret_cast<__half2*>(&g.z);
    __half2 q3 = *reinterpret_cast<__half2*>(&g.w);
    float2 f0 = __half22float2(q0), f1 = __half22float2(q1);
    float2 f2 = __half22float2(q2), f3 = __half22float2(q3);
    atomicAdd(&cnt[l], 1);
    atomicAdd(&tile[0 * RW + l], f0.x);
    atomicAdd(&tile[1 * RW + l], f0.y);
    atomicAdd(&tile[2 * RW + l], f1.x);
    atomicAdd(&tile[3 * RW + l], f1.y);
    atomicAdd(&tile[4 * RW + l], f2.x);
    atomicAdd(&tile[5 * RW + l], f2.y);
    atomicAdd(&tile[6 * RW + l], f3.x);
    atomicAdd(&tile[7 * RW + l], f3.y);
}

__global__ __launch_bounds__(256) void agg1_kernel(const unsigned int* __restrict__ bucket_d,
        const int* __restrict__ base_d, const uint4* __restrict__ h4,
        float* __restrict__ pagg1, int* __restrict__ pcnt) {
    __shared__ float tile[HID * RW];
    __shared__ int cnt[RW];
    int r = blockIdx.x, s = blockIdx.y, t = threadIdx.x;
    for (int i = t; i < HID * RW; i += 256) tile[i] = 0.f;
    if (t < RW) cnt[t] = 0;
    __syncthreads();
    int L = base_d[r], H = base_d[r + 1], len = H - L;
    int lo = L + (int)((long long)len * s / SEG);
    int hi = L + (int)((long long)len * (s + 1) / SEG);
    int i = lo + t;
    for (; i + 768 < hi; i += 1024) {
        unsigned p0 = bucket_d[i], p1 = bucket_d[i + 256], p2 = bucket_d[i + 512], p3 = bucket_d[i + 768];
        uint4 g0 = h4[p0 >> 7], g1 = h4[p1 >> 7], g2 = h4[p2 >> 7], g3 = h4[p3 >> 7];
        addEdge1(tile, cnt, p0, g0);
        addEdge1(tile, cnt, p1, g1);
        addEdge1(tile, cnt, p2, g2);
        addEdge1(tile, cnt, p3, g3);
    }
    for (; i < hi; i += 256) {
        unsigned p = bucket_d[i];
        uint4 g = h4[p >> 7];
        addEdge1(tile, cnt, p, g);
    }
    __syncthreads();
    float* pb = pagg1 + (size_t)(r * SEG + s) * (HID * RW);
    for (int k = t; k < HID * RW; k += 256) pb[k] = tile[k];
    if (t < RW) pcnt[(size_t)(r * SEG + s) * RW + t] = cnt[t];
}

// ---------------- combine1: sum partials, deg_in, norm, bias, relu, W2 dot -> h2 ----------------
__global__ __launch_bounds__(RW) void combine1_kernel(const float* __restrict__ pagg1,
        const int* __restrict__ pcnt, const float* __restrict__ deg_out,
        const float* __restrict__ b1, const float* __restrict__ W2,
        float* __restrict__ h2, float* __restrict__ deg_in, int N) {
    int r = blockIdx.x, l = threadIdx.x;
    float acc[HID];
    #pragma unroll
    for (int j = 0; j < HID; ++j) acc[j] = 0.f;
    int c = 0;
    for (int s = 0; s < SEG; ++s) {
        const float* pb = pagg1 + (size_t)(r * SEG + s) * (HID * RW);
        #pragma unroll
        for (int j = 0; j < HID; ++j) acc[j] += pb[j * RW + l];
        c += pcnt[(size_t)(r * SEG + s) * RW + l];
    }
    int node = r * RW + l;
    if (node < N) {
        float din = (float)c;
        deg_in[node] = din;
        float nin = rsqrtf(fmaxf(din, 1.f));
        float nout = rsqrtf(fmaxf(deg_out[node], 1.f));
        float dot = 0.f;
        #pragma unroll
        for (int j = 0; j < HID; ++j) {
            float y = fmaxf(acc[j] * nin + b1[j], 0.f);
            dot += y * W2[j];
        }
        h2[node] = dot * nout;
    }
}

// ---------------- agg2: segmented 1-float aggregation ----------------
__global__ __launch_bounds__(256) void agg2_kernel(const unsigned int* __restrict__ bucket_d,
        const int* __restrict__ base_d, const float* __restrict__ h2,
        float* __restrict__ pagg2) {
    __shared__ float tile[RW];
    int r = blockIdx.x, s = blockIdx.y, t = threadIdx.x;
    if (t < RW) tile[t] = 0.f;
    __syncthreads();
    int L = base_d[r], H = base_d[r + 1], len = H - L;
    int lo = L + (int)((long long)len * s / SEG);
    int hi = L + (int)((long long)len * (s + 1) / SEG);
    int i = lo + t;
    for (; i + 768 < hi; i += 1024) {
        unsigned p0 = bucket_d[i], p1 = bucket_d[i + 256], p2 = bucket_d[i + 512], p3 = bucket_d[i + 768];
        float v0 = h2[p0 >> 7], v1 = h2[p1 >> 7], v2 = h2[p2 >> 7], v3 = h2[p3 >> 7];
        atomicAdd(&tile[p0 & 127], v0);
        atomicAdd(&tile[p1 & 127], v1);
        atomicAdd(&tile[p2 & 127], v2);
        atomicAdd(&tile[p3 & 127], v3);
    }
    for (; i < hi; i += 256) {
        unsigned p = bucket_d[i];
        atomicAdd(&tile[p & 127], h2[p >> 7]);
    }
    __syncthreads();
    if (t < RW) pagg2[(size_t)(r * SEG + s) * RW + t] = tile[t];
}

// ---------------- final: combine agg2 partials, norm_in, bias -> out ----------------
__global__ __launch_bounds__(RW) void final_kernel(const float* __restrict__ pagg2,
        const float* __restrict__ deg_in, const float* __restrict__ b2,
        float* __restrict__ out, int N) {
    int r = blockIdx.x, l = threadIdx.x;
    float a = 0.f;
    for (int s = 0; s < SEG; ++s) a += pagg2[(size_t)(r * SEG + s) * RW + l];
    int node = r * RW + l;
    if (node < N) out[node] = a * rsqrtf(fmaxf(deg_in[node], 1.f)) + b2[0];
}

extern "C" void kernel_launch(void* const* d_in, const int* in_sizes, int n_in,
                              void* d_out, int out_size, void* d_ws, size_t ws_size,
                              hipStream_t stream) {
    const float* x  = (const float*)d_in[0];
    const int* src  = (const int*)d_in[1];
    const int* dst  = (const int*)d_in[2];
    const float* W1 = (const float*)d_in[3];
    const float* b1 = (const float*)d_in[4];
    const float* W2 = (const float*)d_in[5];
    const float* b2 = (const float*)d_in[6];
    float* out = (float*)d_out;

    const int N = out_size;      // 100000
    const int E = in_sizes[1];   // 3200000
    const int R = (N + RW - 1) / RW;          // 782
    const int chunk = (E + CCH - 1) / CCH;    // 6250

    // workspace layout (all regions fully written by kernels before use; no memset)
    float* ws      = (float*)d_ws;
    float* deg_out = ws;                        // N
    float* deg_in  = deg_out + N;               // N
    float* h2      = deg_in + N;                // N
    float* pagg1   = h2 + N;                    // R*SEG*HID*RW
    float* pagg2   = pagg1 + (size_t)R * SEG * HID * RW;  // R*SEG*RW
    int*   pcnt    = (int*)(pagg2 + (size_t)R * SEG * RW);// R*SEG*RW
    int*   cnt_d   = pcnt + (size_t)R * SEG * RW;         // CCH*R
    int*   cnt_s   = cnt_d + (size_t)CCH * R;   // CCH*R
    int*   tot_d   = cnt_s + (size_t)CCH * R;   // R
    int*   tot_s   = tot_d + R;                 // R
    int*   base_d  = tot_s + R;                 // R+1
    int*   base_s  = base_d + R + 1;            // R+1
    uint4* h4      = (uint4*)(((uintptr_t)(base_s + R + 1) + 15) & ~(uintptr_t)15); // N uint4
    unsigned int*  bucket_d = (unsigned int*)(h4 + N);           // E
    unsigned char* bucket_s = (unsigned char*)(bucket_d + E);    // E bytes

    pass1_count<<<CCH, 256, 0, stream>>>(src, dst, cnt_d, cnt_s, E, R, chunk);
    scan1_kernel<<<dim3(R, 2), 256, 0, stream>>>(cnt_d, cnt_s, tot_d, tot_s, R);
    scan2_kernel<<<2, 256, 0, stream>>>(tot_d, tot_s, base_d, base_s, R);
    scatter_kernel<<<CCH, 256, 0, stream>>>(src, dst, cnt_d, cnt_s, base_d, base_s,
                                            bucket_d, bucket_s, E, R, chunk);
    degout_kernel<<<R, 256, 0, stream>>>(bucket_s, base_s, deg_out, N);
    conv1_kernel<<<(N + 31) / 32, 256, 0, stream>>>(x, W1, deg_out, h4, N);
    agg1_kernel<<<dim3(R, SEG), 256, 0, stream>>>(bucket_d, base_d, h4, pagg1, pcnt);
    combine1_kernel<<<R, RW, 0, stream>>>(pagg1, pcnt, deg_out, b1, W2, h2, deg_in, N);
    agg2_kernel<<<dim3(R, SEG), 256, 0, stream>>>(bucket_d, base_d, h2, pagg2);
    final_kernel<<<R, RW, 0, stream>>>(pagg2, deg_in, b2, out, N);
}